// Round 5
// baseline (817.401 us; speedup 1.0000x reference)
//
#include <hip/hip_runtime.h>

// CapsuleLayer dynamic routing — two-phase, fp32-exact.
//   P[k,b,r,o] = sum_c x[b,r,c] * w[k,r,c,o]   (K=B=32, R=2048, C=16, O=32)
//   u0 = sigmoid(colsum(P)/R); f(v) = P^T softmax(P v)
//   u1 = sigmoid(f(u0)); out = sigmoid(f(u0+u1))
//
// R4 post-mortem: priors latency-bound (VALUBusy 8%, HBM 28%, occupancy 19%)
// and P-writes fully drained to HBM (KCHUNK=16 working set ~ L3 size).
// R5: (1) KCHUNK=8 -> chunk set 96 MB << L3, P buffer reused across chunks so
// dirty lines stay L3-resident; (2) priors rebuilt for occupancy: 4b x 8o
// thread tile (acc 32 VGPR), one row/thread, 8-row blocks, grid 2048/chunk.
// Route kernel (L3-bound) unchanged from R3/R4 (verified).

#define KK 32
#define BB 32
#define RR 2048
#define CC 16
#define OO 32

__device__ __forceinline__ float sigmoidf_(float v) {
  return 1.0f / (1.0f + __expf(-v));
}

// ---------------- Phase 0: x[B][R][C] -> xT[R][C][B] (once) ----------------
__global__ void __launch_bounds__(256)
transpose_x(const float* __restrict__ x, float* __restrict__ xT) {
  const int r = blockIdx.x;          // 0..2047
  const int t = threadIdx.x;
  const int b = t >> 3;              // 0..31
  const int c = (t & 7) * 2;         // 0,2,..,14
  const float2 v = *(const float2*)(x + ((size_t)b * RR + r) * CC + c);
  xT[((size_t)r * CC + c) * BB + b]     = v.x;
  xT[((size_t)r * CC + c + 1) * BB + b] = v.y;
}

// ---------------- Phase 1: priors einsum (occupancy-tuned) ----------------
// grid = KCHUNK*256 blocks x 256 thr. Block = (kl = bid>>8, 8-row tile).
// Lane: og = l&3 (8 o), bq = (l>>2)&7 (4 b), rw = l>>5; row = rt*8+wid*2+rw.
// Thread tile 4b x 8o -> acc 32 VGPR. w row read ONCE per chunk (og-lane
// broadcast over bq groups). x from xT[R][C][B] (b contiguous).
__global__ void __launch_bounds__(256, 5)
capsule_priors2(const float* __restrict__ xT, const float* __restrict__ w,
                float* __restrict__ P, int k0) {
  const int bid  = blockIdx.x;
  const int kl   = bid >> 8;
  const int rt   = bid & 255;        // 0..255, 8 rows each
  const int t    = threadIdx.x;
  const int lane = t & 63;
  const int wid  = t >> 6;           // 0..3
  const int og   = lane & 3;
  const int bq   = (lane >> 2) & 7;
  const int rw   = lane >> 5;        // 0..1
  const int r    = rt * 8 + wid * 2 + rw;
  const int k    = k0 + kl;

  const float* __restrict__ xr = xT + ((size_t)r * CC) * BB + bq * 4;
  const float* __restrict__ wr = w + (size_t)k * ((size_t)RR * CC * OO)
                                   + ((size_t)r * CC) * OO + og * 8;

  float4 a[4][2];
  #pragma unroll
  for (int bb = 0; bb < 4; ++bb) {
    a[bb][0] = make_float4(0.f, 0.f, 0.f, 0.f);
    a[bb][1] = make_float4(0.f, 0.f, 0.f, 0.f);
  }

  #pragma unroll
  for (int c = 0; c < CC; ++c) {
    const float4 xf = *(const float4*)(xr + c * BB);
    const float4 w0 = *(const float4*)(wr + c * OO);
    const float4 w1 = *(const float4*)(wr + c * OO + 4);
    const float xs[4] = {xf.x, xf.y, xf.z, xf.w};
    #pragma unroll
    for (int bb = 0; bb < 4; ++bb) {
      const float s = xs[bb];
      a[bb][0].x = fmaf(s, w0.x, a[bb][0].x);
      a[bb][0].y = fmaf(s, w0.y, a[bb][0].y);
      a[bb][0].z = fmaf(s, w0.z, a[bb][0].z);
      a[bb][0].w = fmaf(s, w0.w, a[bb][0].w);
      a[bb][1].x = fmaf(s, w1.x, a[bb][1].x);
      a[bb][1].y = fmaf(s, w1.y, a[bb][1].y);
      a[bb][1].z = fmaf(s, w1.z, a[bb][1].z);
      a[bb][1].w = fmaf(s, w1.w, a[bb][1].w);
    }
  }

  #pragma unroll
  for (int bb = 0; bb < 4; ++bb) {
    const int b = bq * 4 + bb;
    float* Pd = P + (((size_t)kl * BB + b) * RR + r) * OO + og * 8;
    *(float4*)(Pd)     = a[bb][0];
    *(float4*)(Pd + 4) = a[bb][1];
  }
}

// ---------------- Phase 2: routing (unchanged from R3/R4, verified) -------
__global__ void __launch_bounds__(1024, 4)
capsule_route(const float* __restrict__ P, float* __restrict__ out, int k0) {
  __shared__ float swv[512];
  __shared__ float sU[32];
  __shared__ float sM[16];
  __shared__ float sZ[16];

  const int bid  = blockIdx.x;
  const int kl   = bid >> 5;
  const int b    = bid & 31;
  const int t    = threadIdx.x;
  const int o4   = t & 7;
  const int G    = t >> 3;
  const int lane = t & 63;
  const int wid  = t >> 6;

  const float* __restrict__ Pb = P + ((size_t)kl * BB + b) * ((size_t)RR * OO);

  float4 preg[16];
  float4 cs = make_float4(0.f, 0.f, 0.f, 0.f);
  #pragma unroll
  for (int j = 0; j < 16; ++j) {
    preg[j] = *(const float4*)(Pb + (size_t)(j * 128 + G) * OO + (o4 << 2));
    cs.x += preg[j].x; cs.y += preg[j].y; cs.z += preg[j].z; cs.w += preg[j].w;
  }

  #pragma unroll
  for (int m = 8; m <= 32; m <<= 1) {
    cs.x += __shfl_xor(cs.x, m);
    cs.y += __shfl_xor(cs.y, m);
    cs.z += __shfl_xor(cs.z, m);
    cs.w += __shfl_xor(cs.w, m);
  }
  if (lane < 8) *(float4*)&swv[(wid << 5) + (o4 << 2)] = cs;
  __syncthreads();
  if (t < OO) {
    float s = 0.f;
    #pragma unroll
    for (int w2 = 0; w2 < 16; ++w2) s += swv[(w2 << 5) + t];
    sU[t] = sigmoidf_(s * (1.0f / 2048.0f));
  }
  __syncthreads();

  #pragma unroll 1
  for (int pass = 0; pass < 2; ++pass) {
    const float4 v = *(const float4*)&sU[o4 << 2];

    float d[16];
    #pragma unroll
    for (int j = 0; j < 16; ++j) {
      d[j] = preg[j].x * v.x + preg[j].y * v.y + preg[j].z * v.z + preg[j].w * v.w;
    }
    #pragma unroll
    for (int j = 0; j < 16; ++j) {
      d[j] += __shfl_xor(d[j], 1);
      d[j] += __shfl_xor(d[j], 2);
      d[j] += __shfl_xor(d[j], 4);
    }

    float mx = d[0];
    #pragma unroll
    for (int j = 1; j < 16; ++j) mx = fmaxf(mx, d[j]);
    mx = fmaxf(mx, __shfl_xor(mx, 8));
    mx = fmaxf(mx, __shfl_xor(mx, 16));
    mx = fmaxf(mx, __shfl_xor(mx, 32));
    if (lane == 0) sM[wid] = mx;
    __syncthreads();
    float M = sM[0];
    #pragma unroll
    for (int w2 = 1; w2 < 16; ++w2) M = fmaxf(M, sM[w2]);

    float z = 0.f;
    float4 acc = make_float4(0.f, 0.f, 0.f, 0.f);
    #pragma unroll
    for (int j = 0; j < 16; ++j) { d[j] = __expf(d[j] - M); z += d[j]; }
    #pragma unroll
    for (int j = 0; j < 16; ++j) {
      acc.x = fmaf(d[j], preg[j].x, acc.x);
      acc.y = fmaf(d[j], preg[j].y, acc.y);
      acc.z = fmaf(d[j], preg[j].z, acc.z);
      acc.w = fmaf(d[j], preg[j].w, acc.w);
    }
    #pragma unroll
    for (int m = 8; m <= 32; m <<= 1) {
      z     += __shfl_xor(z, m);
      acc.x += __shfl_xor(acc.x, m);
      acc.y += __shfl_xor(acc.y, m);
      acc.z += __shfl_xor(acc.z, m);
      acc.w += __shfl_xor(acc.w, m);
    }
    if (lane < 8) {
      *(float4*)&swv[(wid << 5) + (o4 << 2)] = acc;
      if (o4 == 0) sZ[wid] = z;
    }
    __syncthreads();
    if (t < OO) {
      float zz = 0.f, s = 0.f;
      #pragma unroll
      for (int w2 = 0; w2 < 16; ++w2) { zz += sZ[w2]; s += swv[(w2 << 5) + t]; }
      const float fo = s / zz;
      if (pass == 0) {
        sU[t] += sigmoidf_(fo);
      } else {
        out[((size_t)((k0 + kl) * BB + b)) * OO + t] = sigmoidf_(fo);
      }
    }
    __syncthreads();
  }
}

// ---------------- Fallback: round-1 fused kernel (verified, 226 us) --------
#define THREADS 1024
#define PLDS_FLOATS (1024 * 32)
#define SWV_OFF PLDS_FLOATS
#define SU_OFF (SWV_OFF + 16 * 32)
#define SM_OFF (SU_OFF + 32)
#define SZ_OFF (SM_OFF + 16)
#define SMEM_FLOATS (SZ_OFF + 16)
#define SMEM_BYTES (SMEM_FLOATS * 4)

__global__ void __launch_bounds__(THREADS, 4)
capsule_fused(const float* __restrict__ x, const float* __restrict__ w,
              float* __restrict__ out) {
  extern __shared__ float smem[];
  float* Plds = smem;
  float* swv  = smem + SWV_OFF;
  float* sU   = smem + SU_OFF;
  float* sM   = smem + SM_OFF;
  float* sZ   = smem + SZ_OFF;

  const int t    = threadIdx.x;
  const int o4   = t & 7;
  const int G    = t >> 3;
  const int lane = t & 63;
  const int wid  = t >> 6;
  const int swz  = ((o4 ^ (G & 7)) << 2);

  const int bid  = blockIdx.x;
  const int xcd  = bid & 7;
  const int slot = bid >> 3;
  const int k    = xcd + 8 * (slot >> 5);
  const int b    = slot & 31;

  const float* __restrict__ xb = x + (size_t)b * (RR * CC);
  const float* __restrict__ wk = w + (size_t)k * ((size_t)RR * CC * OO);

  float4 preg[8];
  float4 cs = make_float4(0.f, 0.f, 0.f, 0.f);

  #pragma unroll
  for (int j = 0; j < 16; ++j) {
    const int r = ((j & 8) ? 1024 : 0) + 8 * G + (j & 7);
    const float* xr = xb + r * CC;
    float xs[16];
    *(float4*)&xs[0]  = *(const float4*)(xr + 0);
    *(float4*)&xs[4]  = *(const float4*)(xr + 4);
    *(float4*)&xs[8]  = *(const float4*)(xr + 8);
    *(float4*)&xs[12] = *(const float4*)(xr + 12);
    const float* wr = wk + (size_t)r * (CC * OO) + (o4 << 2);
    float4 a = make_float4(0.f, 0.f, 0.f, 0.f);
    #pragma unroll
    for (int c = 0; c < CC; ++c) {
      const float4 wv = *(const float4*)(wr + c * OO);
      a.x = fmaf(xs[c], wv.x, a.x);
      a.y = fmaf(xs[c], wv.y, a.y);
      a.z = fmaf(xs[c], wv.z, a.z);
      a.w = fmaf(xs[c], wv.w, a.w);
    }
    if (j < 8) {
      *(float4*)&Plds[((8 * G + (j & 7)) << 5) + swz] = a;
    } else {
      preg[j - 8] = a;
    }
    cs.x += a.x; cs.y += a.y; cs.z += a.z; cs.w += a.w;
  }

  #pragma unroll
  for (int m = 8; m <= 32; m <<= 1) {
    cs.x += __shfl_xor(cs.x, m);
    cs.y += __shfl_xor(cs.y, m);
    cs.z += __shfl_xor(cs.z, m);
    cs.w += __shfl_xor(cs.w, m);
  }
  if (lane < 8) *(float4*)&swv[(wid << 5) + (o4 << 2)] = cs;
  __syncthreads();
  if (t < OO) {
    float s = 0.f;
    #pragma unroll
    for (int w2 = 0; w2 < 16; ++w2) s += swv[(w2 << 5) + t];
    sU[t] = sigmoidf_(s * (1.0f / 2048.0f));
  }
  __syncthreads();

  #pragma unroll 1
  for (int pass = 0; pass < 2; ++pass) {
    const float4 v = *(const float4*)&sU[o4 << 2];
    float d[16];
    #pragma unroll
    for (int j = 0; j < 8; ++j) {
      const float4 p = *(const float4*)&Plds[((8 * G + j) << 5) + swz];
      d[j] = p.x * v.x + p.y * v.y + p.z * v.z + p.w * v.w;
    }
    #pragma unroll
    for (int j = 0; j < 8; ++j) {
      const float4 p = preg[j];
      d[8 + j] = p.x * v.x + p.y * v.y + p.z * v.z + p.w * v.w;
    }
    #pragma unroll
    for (int j = 0; j < 16; ++j) {
      d[j] += __shfl_xor(d[j], 1);
      d[j] += __shfl_xor(d[j], 2);
      d[j] += __shfl_xor(d[j], 4);
    }
    float mx = d[0];
    #pragma unroll
    for (int j = 1; j < 16; ++j) mx = fmaxf(mx, d[j]);
    mx = fmaxf(mx, __shfl_xor(mx, 8));
    mx = fmaxf(mx, __shfl_xor(mx, 16));
    mx = fmaxf(mx, __shfl_xor(mx, 32));
    if (lane == 0) sM[wid] = mx;
    __syncthreads();
    float M = sM[0];
    #pragma unroll
    for (int w2 = 1; w2 < 16; ++w2) M = fmaxf(M, sM[w2]);

    float z = 0.f;
    float4 acc = make_float4(0.f, 0.f, 0.f, 0.f);
    #pragma unroll
    for (int j = 0; j < 16; ++j) { d[j] = __expf(d[j] - M); z += d[j]; }
    #pragma unroll
    for (int j = 0; j < 8; ++j) {
      const float4 p = *(const float4*)&Plds[((8 * G + j) << 5) + swz];
      acc.x = fmaf(d[j], p.x, acc.x);
      acc.y = fmaf(d[j], p.y, acc.y);
      acc.z = fmaf(d[j], p.z, acc.z);
      acc.w = fmaf(d[j], p.w, acc.w);
    }
    #pragma unroll
    for (int j = 0; j < 8; ++j) {
      const float4 p = preg[j];
      acc.x = fmaf(d[8 + j], p.x, acc.x);
      acc.y = fmaf(d[8 + j], p.y, acc.y);
      acc.z = fmaf(d[8 + j], p.z, acc.z);
      acc.w = fmaf(d[8 + j], p.w, acc.w);
    }
    #pragma unroll
    for (int m = 8; m <= 32; m <<= 1) {
      z     += __shfl_xor(z, m);
      acc.x += __shfl_xor(acc.x, m);
      acc.y += __shfl_xor(acc.y, m);
      acc.z += __shfl_xor(acc.z, m);
      acc.w += __shfl_xor(acc.w, m);
    }
    if (lane < 8) {
      *(float4*)&swv[(wid << 5) + (o4 << 2)] = acc;
      if (o4 == 0) sZ[wid] = z;
    }
    __syncthreads();
    if (t < OO) {
      float zz = 0.f, s = 0.f;
      #pragma unroll
      for (int w2 = 0; w2 < 16; ++w2) { zz += sZ[w2]; s += swv[(w2 << 5) + t]; }
      const float fo = s / zz;
      if (pass == 0) {
        sU[t] = sU[t] + sigmoidf_(fo);
      } else {
        out[((k << 5) + b) * OO + t] = sigmoidf_(fo);
      }
    }
    __syncthreads();
  }
}

extern "C" void kernel_launch(void* const* d_in, const int* in_sizes, int n_in,
                              void* d_out, int out_size, void* d_ws, size_t ws_size,
                              hipStream_t stream) {
  const float* x = (const float*)d_in[0];
  const float* w = (const float*)d_in[1];
  float* out = (float*)d_out;
  (void)in_sizes; (void)n_in; (void)out_size;

  const size_t perK = (size_t)BB * RR * OO * sizeof(float);  // 8 MB per k
  const size_t xTsz = (size_t)BB * RR * CC * sizeof(float);  // 4 MB
  int KCHUNK = 0;
  if      (ws_size >= 8 * perK + xTsz) KCHUNK = 8;   // 68 MB: chunk set << L3
  else if (ws_size >= 4 * perK + xTsz) KCHUNK = 4;   // 36 MB

  if (KCHUNK == 0) {
    hipFuncSetAttribute(reinterpret_cast<const void*>(capsule_fused),
                        hipFuncAttributeMaxDynamicSharedMemorySize, SMEM_BYTES);
    capsule_fused<<<dim3(KK * BB), dim3(THREADS), SMEM_BYTES, stream>>>(x, w, out);
    return;
  }

  float* P  = (float*)d_ws;
  float* xT = (float*)((char*)d_ws + KCHUNK * perK);

  transpose_x<<<dim3(RR), dim3(256), 0, stream>>>(x, xT);
  for (int k0 = 0; k0 < KK; k0 += KCHUNK) {
    capsule_priors2<<<dim3(KCHUNK * 256), dim3(256), 0, stream>>>(xT, w, P, k0);
    capsule_route<<<dim3(KCHUNK * 32), dim3(1024), 0, stream>>>(P, out, k0);
  }
}

// Round 6
// 178.812 us; speedup vs baseline: 4.5713x; 4.5713x over previous
//
#include <hip/hip_runtime.h>

// CapsuleLayer dynamic routing — two-phase, fp32-exact.
//   P[k,b,r,o] = sum_c x[b,r,c] * w[k,r,c,o]   (K=B=32, R=2048, C=16, O=32)
//   u0 = sigmoid(colsum(P)/R); f(v) = P^T softmax(P v)
//   u1 = sigmoid(f(u0)); out = sigmoid(f(u0+u1))
//
// R5 post-mortem: new lane geometry caused 5x HBM amplification (FETCH 293 MB
// vs 36 MB unique) — reverted. R6: R4's counter-validated einsum geometry
// (FETCH~w, WRITE~P, no amplification), row-tile 32->16 so KCHUNK=8 keeps the
// same 1024-block grid (4 blocks/CU). Hypothesis under test: 64 MB P buffer
// reused across 4 chunks stays MALL-resident -> priors WRITE_SIZE collapses.

#define KK 32
#define BB 32
#define RR 2048
#define CC 16
#define OO 32

__device__ __forceinline__ float sigmoidf_(float v) {
  return 1.0f / (1.0f + __expf(-v));
}

// ---------------- Phase 0: x[B][R][C] -> xT[R][C][B] (once) ----------------
__global__ void __launch_bounds__(256)
transpose_x(const float* __restrict__ x, float* __restrict__ xT) {
  const int r = blockIdx.x;          // 0..2047
  const int t = threadIdx.x;
  const int b = t >> 3;              // 0..31
  const int c = (t & 7) * 2;         // 0,2,..,14
  const float2 v = *(const float2*)(x + ((size_t)b * RR + r) * CC + c);
  xT[((size_t)r * CC + c) * BB + b]     = v.x;
  xT[((size_t)r * CC + c + 1) * BB + b] = v.y;
}

// ---------------- Phase 1: priors einsum (R4 geometry, 16-row tiles) -------
// grid = KCHUNK*128 x 256 thr. Block = (kl = bid>>7, 16-row tile rt).
// Lane: og = l&3, bg = (l>>2)&3, rq = l>>4; wave wid owns rows wid*4+rq.
// Thread tile 8b x 8o (acc 64 VGPR). Identical per-instruction load/store
// pattern to R4's verified kernel (no memory amplification).
__global__ void __launch_bounds__(256)
capsule_priors3(const float* __restrict__ xT, const float* __restrict__ w,
                float* __restrict__ P, int k0) {
  const int bid  = blockIdx.x;
  const int kl   = bid >> 7;
  const int rt   = bid & 127;
  const int t    = threadIdx.x;
  const int lane = t & 63;
  const int wid  = t >> 6;           // 0..3
  const int og   = lane & 3;
  const int bg   = (lane >> 2) & 3;
  const int rq   = lane >> 4;        // 0..3
  const int r    = rt * 16 + wid * 4 + rq;
  const int k    = k0 + kl;

  const float* __restrict__ xr = xT + ((size_t)r * CC) * BB + bg * 8;
  const float* __restrict__ wr = w + (size_t)k * ((size_t)RR * CC * OO)
                                   + ((size_t)r * CC) * OO + og * 8;

  float4 acc[8][2];
  #pragma unroll
  for (int bb = 0; bb < 8; ++bb) {
    acc[bb][0] = make_float4(0.f, 0.f, 0.f, 0.f);
    acc[bb][1] = make_float4(0.f, 0.f, 0.f, 0.f);
  }

  #pragma unroll
  for (int c = 0; c < CC; ++c) {
    const float4 xf0 = *(const float4*)(xr + c * BB);
    const float4 xf1 = *(const float4*)(xr + c * BB + 4);
    const float4 wf0 = *(const float4*)(wr + c * OO);
    const float4 wf1 = *(const float4*)(wr + c * OO + 4);
    const float xs[8] = {xf0.x, xf0.y, xf0.z, xf0.w, xf1.x, xf1.y, xf1.z, xf1.w};
    #pragma unroll
    for (int bb = 0; bb < 8; ++bb) {
      const float s = xs[bb];
      acc[bb][0].x = fmaf(s, wf0.x, acc[bb][0].x);
      acc[bb][0].y = fmaf(s, wf0.y, acc[bb][0].y);
      acc[bb][0].z = fmaf(s, wf0.z, acc[bb][0].z);
      acc[bb][0].w = fmaf(s, wf0.w, acc[bb][0].w);
      acc[bb][1].x = fmaf(s, wf1.x, acc[bb][1].x);
      acc[bb][1].y = fmaf(s, wf1.y, acc[bb][1].y);
      acc[bb][1].z = fmaf(s, wf1.z, acc[bb][1].z);
      acc[bb][1].w = fmaf(s, wf1.w, acc[bb][1].w);
    }
  }

  #pragma unroll
  for (int bb = 0; bb < 8; ++bb) {
    const int b = bg * 8 + bb;
    float* Pd = P + (((size_t)kl * BB + b) * RR + r) * OO + og * 8;
    *(float4*)(Pd)     = acc[bb][0];
    *(float4*)(Pd + 4) = acc[bb][1];
  }
}

// ---------------- Phase 2: routing (unchanged from R3/R4, verified) -------
__global__ void __launch_bounds__(1024, 4)
capsule_route(const float* __restrict__ P, float* __restrict__ out, int k0) {
  __shared__ float swv[512];
  __shared__ float sU[32];
  __shared__ float sM[16];
  __shared__ float sZ[16];

  const int bid  = blockIdx.x;
  const int kl   = bid >> 5;
  const int b    = bid & 31;
  const int t    = threadIdx.x;
  const int o4   = t & 7;
  const int G    = t >> 3;
  const int lane = t & 63;
  const int wid  = t >> 6;

  const float* __restrict__ Pb = P + ((size_t)kl * BB + b) * ((size_t)RR * OO);

  float4 preg[16];
  float4 cs = make_float4(0.f, 0.f, 0.f, 0.f);
  #pragma unroll
  for (int j = 0; j < 16; ++j) {
    preg[j] = *(const float4*)(Pb + (size_t)(j * 128 + G) * OO + (o4 << 2));
    cs.x += preg[j].x; cs.y += preg[j].y; cs.z += preg[j].z; cs.w += preg[j].w;
  }

  #pragma unroll
  for (int m = 8; m <= 32; m <<= 1) {
    cs.x += __shfl_xor(cs.x, m);
    cs.y += __shfl_xor(cs.y, m);
    cs.z += __shfl_xor(cs.z, m);
    cs.w += __shfl_xor(cs.w, m);
  }
  if (lane < 8) *(float4*)&swv[(wid << 5) + (o4 << 2)] = cs;
  __syncthreads();
  if (t < OO) {
    float s = 0.f;
    #pragma unroll
    for (int w2 = 0; w2 < 16; ++w2) s += swv[(w2 << 5) + t];
    sU[t] = sigmoidf_(s * (1.0f / 2048.0f));
  }
  __syncthreads();

  #pragma unroll 1
  for (int pass = 0; pass < 2; ++pass) {
    const float4 v = *(const float4*)&sU[o4 << 2];

    float d[16];
    #pragma unroll
    for (int j = 0; j < 16; ++j) {
      d[j] = preg[j].x * v.x + preg[j].y * v.y + preg[j].z * v.z + preg[j].w * v.w;
    }
    #pragma unroll
    for (int j = 0; j < 16; ++j) {
      d[j] += __shfl_xor(d[j], 1);
      d[j] += __shfl_xor(d[j], 2);
      d[j] += __shfl_xor(d[j], 4);
    }

    float mx = d[0];
    #pragma unroll
    for (int j = 1; j < 16; ++j) mx = fmaxf(mx, d[j]);
    mx = fmaxf(mx, __shfl_xor(mx, 8));
    mx = fmaxf(mx, __shfl_xor(mx, 16));
    mx = fmaxf(mx, __shfl_xor(mx, 32));
    if (lane == 0) sM[wid] = mx;
    __syncthreads();
    float M = sM[0];
    #pragma unroll
    for (int w2 = 1; w2 < 16; ++w2) M = fmaxf(M, sM[w2]);

    float z = 0.f;
    float4 acc = make_float4(0.f, 0.f, 0.f, 0.f);
    #pragma unroll
    for (int j = 0; j < 16; ++j) { d[j] = __expf(d[j] - M); z += d[j]; }
    #pragma unroll
    for (int j = 0; j < 16; ++j) {
      acc.x = fmaf(d[j], preg[j].x, acc.x);
      acc.y = fmaf(d[j], preg[j].y, acc.y);
      acc.z = fmaf(d[j], preg[j].z, acc.z);
      acc.w = fmaf(d[j], preg[j].w, acc.w);
    }
    #pragma unroll
    for (int m = 8; m <= 32; m <<= 1) {
      z     += __shfl_xor(z, m);
      acc.x += __shfl_xor(acc.x, m);
      acc.y += __shfl_xor(acc.y, m);
      acc.z += __shfl_xor(acc.z, m);
      acc.w += __shfl_xor(acc.w, m);
    }
    if (lane < 8) {
      *(float4*)&swv[(wid << 5) + (o4 << 2)] = acc;
      if (o4 == 0) sZ[wid] = z;
    }
    __syncthreads();
    if (t < OO) {
      float zz = 0.f, s = 0.f;
      #pragma unroll
      for (int w2 = 0; w2 < 16; ++w2) { zz += sZ[w2]; s += swv[(w2 << 5) + t]; }
      const float fo = s / zz;
      if (pass == 0) {
        sU[t] += sigmoidf_(fo);
      } else {
        out[((size_t)((k0 + kl) * BB + b)) * OO + t] = sigmoidf_(fo);
      }
    }
    __syncthreads();
  }
}

// ---------------- Fallback: round-1 fused kernel (verified, 226 us) --------
#define THREADS 1024
#define PLDS_FLOATS (1024 * 32)
#define SWV_OFF PLDS_FLOATS
#define SU_OFF (SWV_OFF + 16 * 32)
#define SM_OFF (SU_OFF + 32)
#define SZ_OFF (SM_OFF + 16)
#define SMEM_FLOATS (SZ_OFF + 16)
#define SMEM_BYTES (SMEM_FLOATS * 4)

__global__ void __launch_bounds__(THREADS, 4)
capsule_fused(const float* __restrict__ x, const float* __restrict__ w,
              float* __restrict__ out) {
  extern __shared__ float smem[];
  float* Plds = smem;
  float* swv  = smem + SWV_OFF;
  float* sU   = smem + SU_OFF;
  float* sM   = smem + SM_OFF;
  float* sZ   = smem + SZ_OFF;

  const int t    = threadIdx.x;
  const int o4   = t & 7;
  const int G    = t >> 3;
  const int lane = t & 63;
  const int wid  = t >> 6;
  const int swz  = ((o4 ^ (G & 7)) << 2);

  const int bid  = blockIdx.x;
  const int xcd  = bid & 7;
  const int slot = bid >> 3;
  const int k    = xcd + 8 * (slot >> 5);
  const int b    = slot & 31;

  const float* __restrict__ xb = x + (size_t)b * (RR * CC);
  const float* __restrict__ wk = w + (size_t)k * ((size_t)RR * CC * OO);

  float4 preg[8];
  float4 cs = make_float4(0.f, 0.f, 0.f, 0.f);

  #pragma unroll
  for (int j = 0; j < 16; ++j) {
    const int r = ((j & 8) ? 1024 : 0) + 8 * G + (j & 7);
    const float* xr = xb + r * CC;
    float xs[16];
    *(float4*)&xs[0]  = *(const float4*)(xr + 0);
    *(float4*)&xs[4]  = *(const float4*)(xr + 4);
    *(float4*)&xs[8]  = *(const float4*)(xr + 8);
    *(float4*)&xs[12] = *(const float4*)(xr + 12);
    const float* wr = wk + (size_t)r * (CC * OO) + (o4 << 2);
    float4 a = make_float4(0.f, 0.f, 0.f, 0.f);
    #pragma unroll
    for (int c = 0; c < CC; ++c) {
      const float4 wv = *(const float4*)(wr + c * OO);
      a.x = fmaf(xs[c], wv.x, a.x);
      a.y = fmaf(xs[c], wv.y, a.y);
      a.z = fmaf(xs[c], wv.z, a.z);
      a.w = fmaf(xs[c], wv.w, a.w);
    }
    if (j < 8) {
      *(float4*)&Plds[((8 * G + (j & 7)) << 5) + swz] = a;
    } else {
      preg[j - 8] = a;
    }
    cs.x += a.x; cs.y += a.y; cs.z += a.z; cs.w += a.w;
  }

  #pragma unroll
  for (int m = 8; m <= 32; m <<= 1) {
    cs.x += __shfl_xor(cs.x, m);
    cs.y += __shfl_xor(cs.y, m);
    cs.z += __shfl_xor(cs.z, m);
    cs.w += __shfl_xor(cs.w, m);
  }
  if (lane < 8) *(float4*)&swv[(wid << 5) + (o4 << 2)] = cs;
  __syncthreads();
  if (t < OO) {
    float s = 0.f;
    #pragma unroll
    for (int w2 = 0; w2 < 16; ++w2) s += swv[(w2 << 5) + t];
    sU[t] = sigmoidf_(s * (1.0f / 2048.0f));
  }
  __syncthreads();

  #pragma unroll 1
  for (int pass = 0; pass < 2; ++pass) {
    const float4 v = *(const float4*)&sU[o4 << 2];
    float d[16];
    #pragma unroll
    for (int j = 0; j < 8; ++j) {
      const float4 p = *(const float4*)&Plds[((8 * G + j) << 5) + swz];
      d[j] = p.x * v.x + p.y * v.y + p.z * v.z + p.w * v.w;
    }
    #pragma unroll
    for (int j = 0; j < 8; ++j) {
      const float4 p = preg[j];
      d[8 + j] = p.x * v.x + p.y * v.y + p.z * v.z + p.w * v.w;
    }
    #pragma unroll
    for (int j = 0; j < 16; ++j) {
      d[j] += __shfl_xor(d[j], 1);
      d[j] += __shfl_xor(d[j], 2);
      d[j] += __shfl_xor(d[j], 4);
    }
    float mx = d[0];
    #pragma unroll
    for (int j = 1; j < 16; ++j) mx = fmaxf(mx, d[j]);
    mx = fmaxf(mx, __shfl_xor(mx, 8));
    mx = fmaxf(mx, __shfl_xor(mx, 16));
    mx = fmaxf(mx, __shfl_xor(mx, 32));
    if (lane == 0) sM[wid] = mx;
    __syncthreads();
    float M = sM[0];
    #pragma unroll
    for (int w2 = 1; w2 < 16; ++w2) M = fmaxf(M, sM[w2]);

    float z = 0.f;
    float4 acc = make_float4(0.f, 0.f, 0.f, 0.f);
    #pragma unroll
    for (int j = 0; j < 16; ++j) { d[j] = __expf(d[j] - M); z += d[j]; }
    #pragma unroll
    for (int j = 0; j < 8; ++j) {
      const float4 p = *(const float4*)&Plds[((8 * G + j) << 5) + swz];
      acc.x = fmaf(d[j], p.x, acc.x);
      acc.y = fmaf(d[j], p.y, acc.y);
      acc.z = fmaf(d[j], p.z, acc.z);
      acc.w = fmaf(d[j], p.w, acc.w);
    }
    #pragma unroll
    for (int j = 0; j < 8; ++j) {
      const float4 p = preg[j];
      acc.x = fmaf(d[8 + j], p.x, acc.x);
      acc.y = fmaf(d[8 + j], p.y, acc.y);
      acc.z = fmaf(d[8 + j], p.z, acc.z);
      acc.w = fmaf(d[8 + j], p.w, acc.w);
    }
    #pragma unroll
    for (int m = 8; m <= 32; m <<= 1) {
      z     += __shfl_xor(z, m);
      acc.x += __shfl_xor(acc.x, m);
      acc.y += __shfl_xor(acc.y, m);
      acc.z += __shfl_xor(acc.z, m);
      acc.w += __shfl_xor(acc.w, m);
    }
    if (lane < 8) {
      *(float4*)&swv[(wid << 5) + (o4 << 2)] = acc;
      if (o4 == 0) sZ[wid] = z;
    }
    __syncthreads();
    if (t < OO) {
      float zz = 0.f, s = 0.f;
      #pragma unroll
      for (int w2 = 0; w2 < 16; ++w2) { zz += sZ[w2]; s += swv[(w2 << 5) + t]; }
      const float fo = s / zz;
      if (pass == 0) {
        sU[t] = sU[t] + sigmoidf_(fo);
      } else {
        out[((k << 5) + b) * OO + t] = sigmoidf_(fo);
      }
    }
    __syncthreads();
  }
}

extern "C" void kernel_launch(void* const* d_in, const int* in_sizes, int n_in,
                              void* d_out, int out_size, void* d_ws, size_t ws_size,
                              hipStream_t stream) {
  const float* x = (const float*)d_in[0];
  const float* w = (const float*)d_in[1];
  float* out = (float*)d_out;
  (void)in_sizes; (void)n_in; (void)out_size;

  const size_t perK = (size_t)BB * RR * OO * sizeof(float);  // 8 MB per k
  const size_t xTsz = (size_t)BB * RR * CC * sizeof(float);  // 4 MB
  int KCHUNK = 0;
  if      (ws_size >= 8 * perK + xTsz) KCHUNK = 8;   // 68 MB working set << MALL
  else if (ws_size >= 4 * perK + xTsz) KCHUNK = 4;

  if (KCHUNK == 0) {
    hipFuncSetAttribute(reinterpret_cast<const void*>(capsule_fused),
                        hipFuncAttributeMaxDynamicSharedMemorySize, SMEM_BYTES);
    capsule_fused<<<dim3(KK * BB), dim3(THREADS), SMEM_BYTES, stream>>>(x, w, out);
    return;
  }

  float* P  = (float*)d_ws;
  float* xT = (float*)((char*)d_ws + KCHUNK * perK);

  transpose_x<<<dim3(RR), dim3(256), 0, stream>>>(x, xT);
  for (int k0 = 0; k0 < KK; k0 += KCHUNK) {
    capsule_priors3<<<dim3(KCHUNK * 128), dim3(256), 0, stream>>>(xT, w, P, k0);
    capsule_route<<<dim3(KCHUNK * 32), dim3(1024), 0, stream>>>(P, out, k0);
  }
}